// Round 16
// baseline (3716.253 us; speedup 1.0000x reference)
//
#include <hip/hip_runtime.h>

// GRU layer, B=64 T=512 D=512 H=1024, TF GRUCell semantics.
// v16 = hybrid exchange: FLAGS always agent-scope sc1 (r10-proven RTT, no
// buffer_inv in the poll loop); DATA sc0-stored (parked in same-XCD L2,
// v14-proven by WRITE_SIZE 270->131MB) + ONE buffer_inv per stage then plain
// loads (L2 hits). Probe = 16-round steady-state through this exact hybrid
// pattern; failure demotes the island to the full agent path (r10, 2.9ms).
// xc Y-loads issued before the rh wait (free overlap; poll has no waitcnt).

typedef __attribute__((ext_vector_type(8))) short          s16x8;
typedef __attribute__((ext_vector_type(4))) float          f32x4;
typedef __attribute__((ext_vector_type(4))) unsigned short us4;
typedef __attribute__((ext_vector_type(8))) unsigned short us8;
typedef unsigned long long ull;
typedef unsigned short us;

#define TT 512
#define DD 512
#define HH 1024
#define WPGE 1032
#define ASTR 1032
#define XSTR 520
#define O_ASH (64 * WPGE)                 // 66048
#define O_XS  (O_ASH + 8 * ASTR)          // 74304
#define O_USH (O_XS + 8 * XSTR)           // 78464 (float[8][36])
#define O_PS  (O_USH + 576)               // 79040 (float[2][8][20])
#define LDS_BYTES ((O_PS + 640) * 2)      // 159360
#define XP_LDSB (64 * 520 * 2 + 16 * 520 * 2)   // 83200

// ws layout (bytes)
#define W_CNT  0             // u32[8] per-XCD WG counters
#define W_PRB  1024          // probe slots: 256 x 64B (flag4 @+0, data8 @+8)
#define W_OKS  17408         // u32[256] per-WG probe verdicts
#define W_VER  18432         // u32[8] island verdicts
#define W_FL   20480         // island isl @ +isl*8192: rA,rB,hA,hB 32x64B each
#define W_HB   86016         // h  bf16 [64][1024] -- memset 0 = h0
#define W_RHB  217088        // rh bf16 [64][1024]
#define W_END  348160
#define CAP_AG (1 << 17)

__device__ __forceinline__ us f2b(float f) {               // f32 -> bf16 RNE
  unsigned u = __float_as_uint(f);
  u += 0x7FFFu + ((u >> 16) & 1u);
  return (us)(u >> 16);
}
__device__ __forceinline__ float b2f(us b) { return __uint_as_float(((unsigned)b) << 16); }

// ---- primitives -------------------------------------------------------------
__device__ __forceinline__ void inv_only() {               // L1 inv, NO vmcnt
  asm volatile("buffer_inv" ::: "memory");
}
__device__ __forceinline__ void drain_vm() {
  asm volatile("s_waitcnt vmcnt(0)" ::: "memory");
}
__device__ __forceinline__ void st8_sc0(void* p, ull v) {
  asm volatile("global_store_dwordx2 %0, %1, off sc0" :: "v"(p), "v"(v) : "memory");
}
// flags: ALWAYS agent scope (r10-proven)
__device__ __forceinline__ void pubfl(unsigned* p, unsigned v) {
  __hip_atomic_store(p, v, __ATOMIC_RELAXED, __HIP_MEMORY_SCOPE_AGENT);
}
// data publish: local L2 (sc0) when loc, else agent
__device__ __forceinline__ void pub8(ull* p, ull v, bool loc) {
  if (loc) st8_sc0(p, v);
  else __hip_atomic_store(p, v, __ATOMIC_RELAXED, __HIP_MEMORY_SCOPE_AGENT);
}
// wait flags in TWO 32-slot arrays (lanes 0-31 -> fA, 32-63 -> fB); agent poll
__device__ __forceinline__ void waitf2(const unsigned* fA, const unsigned* fB,
                                       unsigned e, int lane, bool& bad) {
  if (bad) return;
  const unsigned* p = (lane < 32) ? (fA + lane * 16) : (fB + (lane - 32) * 16);
  int n = 0;
  for (;;) {
    unsigned v = __hip_atomic_load(p, __ATOMIC_RELAXED, __HIP_MEMORY_SCOPE_AGENT);
    if (__all((int)(v >= e))) return;
    if (++n > CAP_AG) { bad = true; return; }
    __builtin_amdgcn_s_sleep(1);
  }
}
// stage 8 rows x 1024 bf16 island buffer -> Ash (thread: row8=tid>>5, lp=tid&31)
__device__ __forceinline__ void stage(const us* g, us* A, int row8, int lp, bool loc) {
  const ull* p = (const ull*)(g + (size_t)row8 * HH) + lp;
  ull r[8];
  if (loc) {
    inv_only();                            // ONE inv; then plain loads hit L2
    #pragma unroll
    for (int j = 0; j < 8; ++j) r[j] = *(volatile const ull*)(p + j * 32);
  } else {
    #pragma unroll
    for (int j = 0; j < 8; ++j)
      r[j] = __hip_atomic_load(p + j * 32, __ATOMIC_RELAXED, __HIP_MEMORY_SCOPE_AGENT);
  }
  us* d = A + row8 * ASTR + lp * 4;
  #pragma unroll
  for (int j = 0; j < 8; ++j) *(ull*)(d + j * 128) = r[j];
}

// in-register 4x4 transpose within a lane quad -> 4 cols of row (r16&3)
__device__ __forceinline__ ull quad_pack(float v0, float v1, float v2, float v3, int q) {
  unsigned p01 = (unsigned)f2b(v0) | ((unsigned)f2b(v1) << 16);
  unsigned p23 = (unsigned)f2b(v2) | ((unsigned)f2b(v3) << 16);
  unsigned o01 = __shfl_xor(p01, 2);
  unsigned o23 = __shfl_xor(p23, 2);
  unsigned x = (q < 2) ? p01 : o23;
  unsigned y = (q < 2) ? o01 : p23;
  unsigned ux = __shfl_xor(x, 1);
  unsigned uy = __shfl_xor(y, 1);
  unsigned w0, w1;
  if (q & 1) { w0 = (ux >> 16) | (x & 0xFFFF0000u); w1 = (uy >> 16) | (y & 0xFFFF0000u); }
  else       { w0 = (x & 0xFFFFu) | (ux << 16);     w1 = (y & 0xFFFFu) | (uy << 16); }
  return (ull)w0 | ((ull)w1 << 32);
}

extern "C" __global__ void __launch_bounds__(256, 1)
gru_persistent(const float* __restrict__ X, const float* __restrict__ GK,
               const float* __restrict__ GB, const float* __restrict__ CK,
               const float* __restrict__ CB, float* __restrict__ Y,
               unsigned char* __restrict__ ws) {
  extern __shared__ us lds[];
  us*    Wg  = lds;                          // [64][WPGE]
  us*    Ash = lds + O_ASH;                  // [8][ASTR]
  us*    Xs  = lds + O_XS;                   // [8][XSTR]
  float* ush = (float*)(lds + O_USH);        // u [8][36] (startup bcast reuse)
  float* ps  = (float*)(lds + O_PS);         // cand partials [2][8][20]

  const int tid = threadIdx.x, bid = blockIdx.x;
  const int lane = tid & 63, w = tid >> 6;
  const int r16 = lane & 15, g4 = lane >> 4;
  const int row8 = tid >> 5, lp = tid & 31;
  const int half = w & 1;
  const int tlB = w >> 1, khB = w & 1;

  unsigned* cnt = (unsigned*)(ws + W_CNT);
  unsigned* prb = (unsigned*)(ws + W_PRB);
  unsigned* oks = (unsigned*)(ws + W_OKS);
  unsigned* ver = (unsigned*)(ws + W_VER);

  // ---- placement-derived roles (1 WG/CU x 256 => exactly 32/XCD) -----------
  if (tid == 0) {
    unsigned xcd = (unsigned)__builtin_amdgcn_s_getreg((31 << 11) | 20) & 7u;
    unsigned slot = __hip_atomic_fetch_add(cnt + xcd, 1u, __ATOMIC_RELAXED,
                                           __HIP_MEMORY_SCOPE_AGENT);
    int n = 0; bool okr = true;
    for (;;) {
      unsigned s = 0;
      #pragma unroll
      for (int x = 0; x < 8; ++x)
        s += __hip_atomic_load(cnt + x, __ATOMIC_RELAXED, __HIP_MEMORY_SCOPE_AGENT);
      if (s >= 256u) break;
      if (++n > (1 << 20)) { okr = false; break; }
      __builtin_amdgcn_s_sleep(2);
    }
    bool dyn = okr;
    if (okr) {
      #pragma unroll
      for (int x = 0; x < 8; ++x)
        dyn = dyn && (__hip_atomic_load(cnt + x, __ATOMIC_RELAXED,
                                        __HIP_MEMORY_SCOPE_AGENT) == 32u);
    }
    unsigned uisl, uiw, um;
    if (dyn) { uisl = xcd; uiw = slot; um = 1u; }
    else     { uisl = (unsigned)(bid & 7); uiw = (unsigned)(bid >> 3); um = 0u; }
    ush[0] = __uint_as_float(uisl);
    ush[1] = __uint_as_float(uiw);
    ush[2] = __uint_as_float(um);
  }
  __syncthreads();
  const int  isl = (int)__float_as_uint(ush[0]);
  const int  iw  = (int)__float_as_uint(ush[1]);
  const bool dynmode = __float_as_uint(ush[2]) != 0u;
  __syncthreads();
  const int cb = iw * 32;

  // ---- 16-round steady-state probe of the HYBRID pattern -------------------
  // producer: sc0 data store -> vmcnt drain -> agent flag
  // consumer: agent flag poll -> buffer_inv -> plain data load
  bool loc = false;
  if (dynmode) {
    unsigned* myslot = prb + (size_t)(isl * 32 + iw) * 16;   // 64B-spaced
    if (w == 0) {
      bool okl = true;
      for (unsigned r = 1; r <= 16u && okl; ++r) {
        if (lane == 0) {
          st8_sc0(myslot + 2, ((ull)r << 32) | r);   // data8 @ +8B (sc0)
          drain_vm();
          __hip_atomic_store(myslot, r, __ATOMIC_RELAXED,
                             __HIP_MEMORY_SCOPE_AGENT);        // agent flag
        }
        int n = 0; bool fok = true;
        for (;;) {                          // agent flag poll (no inv)
          bool ok = true;
          if (lane < 32) {
            const unsigned* q = prb + (size_t)(isl * 32 + lane) * 16;
            ok = (__hip_atomic_load(q, __ATOMIC_RELAXED,
                                    __HIP_MEMORY_SCOPE_AGENT) >= r);
          }
          if (__all((int)ok)) break;
          if (++n > (1 << 14)) { fok = false; break; }
          __builtin_amdgcn_s_sleep(2);
        }
        if (!fok) { okl = false; break; }
        inv_only();                         // one inv, then plain data read
        bool dok = true;
        if (lane < 32) {
          const unsigned* q = prb + (size_t)(isl * 32 + lane) * 16;
          ull d = *(volatile const ull*)(q + 2);
          dok = ((unsigned)(d & 0xFFFFFFFFull) >= r);
        }
        if (!__all((int)dok)) { okl = false; break; }
      }
      if (lane == 0) ush[4] = __uint_as_float(okl ? 1u : 0u);
    }
    __syncthreads();
    const bool okwg = __float_as_uint(ush[4]) != 0u;
    __syncthreads();
    if (tid == 0)
      __hip_atomic_store(oks + isl * 32 + iw, okwg ? 1u : 2u,
                         __ATOMIC_RELAXED, __HIP_MEMORY_SCOPE_AGENT);
    if (iw == 0 && w == 0) {
      bool allok = true;
      if (lane < 32) {
        unsigned v = 0; int n = 0;
        for (;;) {
          v = __hip_atomic_load(oks + isl * 32 + lane, __ATOMIC_RELAXED,
                                __HIP_MEMORY_SCOPE_AGENT);
          if (v) break;
          if (++n > (1 << 20)) { v = 2u; break; }
          __builtin_amdgcn_s_sleep(4);
        }
        allok = (v == 1u);
      }
      bool uni = __all((int)allok);
      if (lane == 0)
        __hip_atomic_store(ver + isl, uni ? 1u : 2u, __ATOMIC_RELAXED,
                           __HIP_MEMORY_SCOPE_AGENT);
    }
    if (tid == 0) {
      unsigned m = 0; int n = 0;
      for (;;) {
        m = __hip_atomic_load(ver + isl, __ATOMIC_RELAXED, __HIP_MEMORY_SCOPE_AGENT);
        if (m) break;
        if (++n > (1 << 20)) { m = 2u; break; }
        __builtin_amdgcn_s_sleep(4);
      }
      ush[5] = __uint_as_float(m);
    }
    __syncthreads();
    loc = (__float_as_uint(ush[5]) == 1u);
    __syncthreads();
  }

  unsigned* rA = (unsigned*)(ws + W_FL + (size_t)isl * 8192);
  unsigned* rB = rA + 512;
  unsigned* hA = rA + 1024;
  unsigned* hB = rA + 1536;
  us* hbI  = (us*)(ws + W_HB)  + (size_t)(isl * 8) * HH;
  us* rhbI = (us*)(ws + W_RHB) + (size_t)(isl * 8) * HH;

  // ---- weights -------------------------------------------------------------
  {
    const int c = tid & 63;
    const size_t gcol = (c < 32) ? (size_t)(cb + c) : (size_t)(1024 + cb + (c - 32));
    for (int k = tid >> 6; k < 1024; k += 4)
      Wg[c * WPGE + k] = f2b(GK[(size_t)(512 + k) * 2048 + gcol]);
  }
  s16x8 wx[16], wc[16];
  {
    const size_t gx = (size_t)(cb + half * 16 + r16) + (w >= 2 ? 1024 : 0);
    #pragma unroll
    for (int c2 = 0; c2 < 16; ++c2) {
      us t0[8];
      #pragma unroll
      for (int e = 0; e < 8; ++e)
        t0[e] = f2b(GK[(size_t)(c2 * 32 + g4 * 8 + e) * 2048 + gx]);
      wx[c2] = (s16x8){(short)t0[0],(short)t0[1],(short)t0[2],(short)t0[3],
                       (short)t0[4],(short)t0[5],(short)t0[6],(short)t0[7]};
    }
  }
  {
    const size_t ccol = (size_t)(cb + tlB * 16 + r16);
    #pragma unroll
    for (int c2 = 0; c2 < 16; ++c2) {
      us t0[8];
      #pragma unroll
      for (int e = 0; e < 8; ++e)
        t0[e] = f2b(CK[(size_t)(512 + khB * 512 + c2 * 32 + g4 * 8 + e) * 1024 + ccol]);
      wc[c2] = (s16x8){(short)t0[0],(short)t0[1],(short)t0[2],(short)t0[3],
                       (short)t0[4],(short)t0[5],(short)t0[6],(short)t0[7]};
    }
  }
  const float biasG = (w < 2) ? GB[cb + half * 16 + r16]
                              : GB[1024 + cb + half * 16 + r16];
  const float biasC = CB[cb + tlB * 16 + r16];

  // ---- recurrence (per-wave flags, 4 barriers/step) ------------------------
  float hreg[4] = {0.f, 0.f, 0.f, 0.f};
  bool bad = false;
  float4 px0, px1, px2, px3;
  {
    const float* s = X + (size_t)(isl * 8 + row8) * TT * DD + lp * 16;
    px0 = *(const float4*)s;       px1 = *(const float4*)(s + 4);
    px2 = *(const float4*)(s + 8); px3 = *(const float4*)(s + 12);
  }

  for (int t = 0; t < TT; ++t) {
    {   // Xs(t) from prefetch regs
      us* xd = Xs + row8 * XSTR + lp * 16;
      us8 v0 = { f2b(px0.x), f2b(px0.y), f2b(px0.z), f2b(px0.w),
                 f2b(px1.x), f2b(px1.y), f2b(px1.z), f2b(px1.w) };
      us8 v1 = { f2b(px2.x), f2b(px2.y), f2b(px2.z), f2b(px2.w),
                 f2b(px3.x), f2b(px3.y), f2b(px3.z), f2b(px3.w) };
      *(us8*)xd = v0; *(us8*)(xd + 8) = v1;
    }
    __syncthreads();                                              // S1

    f32x4 a0 = {0.f,0.f,0.f,0.f}, a1 = {0.f,0.f,0.f,0.f};
    {   // gate x-part (overlaps the h wait)
      const us* arX = Xs + (r16 & 7) * XSTR;
      #pragma unroll
      for (int c2 = 0; c2 < 16; c2 += 2) {
        a0 = __builtin_amdgcn_mfma_f32_16x16x32_bf16(
               *(const s16x8*)(arX + c2 * 32 + g4 * 8), wx[c2], a0, 0, 0, 0);
        a1 = __builtin_amdgcn_mfma_f32_16x16x32_bf16(
               *(const s16x8*)(arX + (c2 + 1) * 32 + g4 * 8), wx[c2 + 1], a1, 0, 0, 0);
      }
    }
    waitf2(hA, hB, (unsigned)t, lane, bad);             // h(t-1) ready
    stage(hbI, Ash, row8, lp, loc);
    __syncthreads();                                              // S2

    {   // gate h-GEMM K=1024
      const us* arB = Ash + (r16 & 7) * ASTR;
      const us* brB = Wg + (w * 16 + r16) * WPGE + g4 * 8;
      #pragma unroll
      for (int c2 = 0; c2 < 32; c2 += 2) {
        a0 = __builtin_amdgcn_mfma_f32_16x16x32_bf16(
               *(const s16x8*)(arB + c2 * 32 + g4 * 8),
               *(const s16x8*)(brB + c2 * 32), a0, 0, 0, 0);
        a1 = __builtin_amdgcn_mfma_f32_16x16x32_bf16(
               *(const s16x8*)(arB + (c2 + 1) * 32 + g4 * 8),
               *(const s16x8*)(brB + (c2 + 1) * 32), a1, 0, 0, 0);
      }
    }
    if (g4 < 2) {
      if (w < 2) {                         // r -> publish r*h
        const int colR = cb + half * 16 + r16;
        float rh[4];
        #pragma unroll
        for (int i = 0; i < 4; ++i) {
          float gg = 1.f / (1.f + __expf(-(a0[i] + a1[i] + biasG)));
          rh[i] = gg * b2f(Ash[(g4 * 4 + i) * ASTR + colR]);
        }
        ull tv = quad_pack(rh[0], rh[1], rh[2], rh[3], r16 & 3);
        pub8((ull*)(rhbI + (size_t)(g4 * 4 + (r16 & 3)) * HH + cb + half * 16 + (r16 & ~3)),
             tv, loc);
      } else {                             // u -> LDS (stays in-WG)
        const int uc = half * 16 + r16;
        #pragma unroll
        for (int i = 0; i < 4; ++i)
          ush[(g4 * 4 + i) * 36 + uc] = 1.f / (1.f + __expf(-(a0[i] + a1[i] + biasG)));
      }
    }
    // per-wave drain + agent flag (no barrier on the flag path)
    if (w == 0) { drain_vm(); if (lane == 0) pubfl(rA + iw * 16, (unsigned)(t + 1)); }
    if (w == 1) { drain_vm(); if (lane == 0) pubfl(rB + iw * 16, (unsigned)(t + 1)); }

    // ---- phase B: cand over r*h ----
    float xc[4];                           // xp_c BEFORE the wait (overlaps it)
    if (khB == 0 && g4 < 2) {
      const int colC = cb + tlB * 16 + r16;
      #pragma unroll
      for (int i = 0; i < 4; ++i)
        xc[i] = Y[((size_t)(isl * 8 + g4 * 4 + i) * TT + t) * HH + colC];
    }
    waitf2(rA, rB, (unsigned)(t + 1), lane, bad);
    stage(rhbI, Ash, row8, lp, loc);
    __syncthreads();                                              // S4

    f32x4 c0 = {0.f,0.f,0.f,0.f}, c1 = {0.f,0.f,0.f,0.f};
    {
      const us* arC = Ash + (r16 & 7) * ASTR + khB * 512;
      #pragma unroll
      for (int c2 = 0; c2 < 16; c2 += 2) {
        c0 = __builtin_amdgcn_mfma_f32_16x16x32_bf16(
               *(const s16x8*)(arC + c2 * 32 + g4 * 8), wc[c2], c0, 0, 0, 0);
        c1 = __builtin_amdgcn_mfma_f32_16x16x32_bf16(
               *(const s16x8*)(arC + (c2 + 1) * 32 + g4 * 8), wc[c2 + 1], c1, 0, 0, 0);
      }
    }
    if (khB == 1 && g4 < 2) {
      #pragma unroll
      for (int i = 0; i < 4; ++i)
        ps[tlB * 160 + (g4 * 4 + i) * 20 + r16] = c0[i] + c1[i];
    }
    __syncthreads();                                              // S5
    if (khB == 0 && g4 < 2) {              // blend + publish h
      const int colC = cb + tlB * 16 + r16;
      float hn[4];
      #pragma unroll
      for (int i = 0; i < 4; ++i) {
        int rr = g4 * 4 + i;
        float cv = tanhf(c0[i] + c1[i] + ps[tlB * 160 + rr * 20 + r16] + xc[i] + biasC);
        float uu = ush[rr * 36 + tlB * 16 + r16];
        hn[i] = uu * hreg[i] + (1.f - uu) * cv;
        hreg[i] = hn[i];
        Y[((size_t)(isl * 8 + rr) * TT + t) * HH + colC] = hn[i];
      }
      ull tv = quad_pack(hn[0], hn[1], hn[2], hn[3], r16 & 3);
      pub8((ull*)(hbI + (size_t)(g4 * 4 + (r16 & 3)) * HH + cb + tlB * 16 + (r16 & ~3)),
           tv, loc);
    }
    if (w == 0) { drain_vm(); if (lane == 0) pubfl(hA + iw * 16, (unsigned)(t + 1)); }
    if (w == 2) { drain_vm(); if (lane == 0) pubfl(hB + iw * 16, (unsigned)(t + 1)); }

    if (t + 1 < TT) {                      // prefetch x(t+1) off the crit path
      const float* s = X + ((size_t)(isl * 8 + row8) * TT + (t + 1)) * DD + lp * 16;
      px0 = *(const float4*)s;       px1 = *(const float4*)(s + 4);
      px2 = *(const float4*)(s + 8); px3 = *(const float4*)(s + 12);
    }
  }
  if (bad && tid == 0) Y[1] = 31337.f;     // visible failure sentinel
}

// ---- one-time x-projection: Y <- f32(X[32768,512] @ CKc[512,1024]) ---------
extern "C" __global__ void __launch_bounds__(256, 1)
xproj_c(const float* __restrict__ X, const float* __restrict__ CK,
        float* __restrict__ Y) {
  extern __shared__ us lds[];
  us* Bc  = lds;                 // [64][520]
  us* Axs = lds + 64 * 520;      // [16][520]
  const int tid = threadIdx.x, lane = tid & 63, w = tid >> 6;
  const int r16 = lane & 15, g4 = lane >> 4;
  const int nt = blockIdx.x & 15, mb = blockIdx.x >> 4;
  const int n0 = nt * 64;
  const int srow = tid >> 4, slp = tid & 15;

  {
    const int c4 = (tid & 15) * 4;
    for (int k = tid >> 4; k < 512; k += 16) {
      float4 v = *(const float4*)(CK + (size_t)k * HH + n0 + c4);
      Bc[(c4 + 0) * 520 + k] = f2b(v.x);  Bc[(c4 + 1) * 520 + k] = f2b(v.y);
      Bc[(c4 + 2) * 520 + k] = f2b(v.z);  Bc[(c4 + 3) * 520 + k] = f2b(v.w);
    }
  }
  __syncthreads();

  for (int mt = 0; mt < 32; ++mt) {
    const size_t m0 = (size_t)mb * 512 + mt * 16;
    {
      const float* src = X + (m0 + srow) * 512 + slp * 4;
      us* d = Axs + srow * 520 + slp * 4;
      #pragma unroll
      for (int j = 0; j < 8; ++j) {
        float4 v = *(const float4*)(src + j * 64);
        us4 p = { f2b(v.x), f2b(v.y), f2b(v.z), f2b(v.w) };
        *(us4*)(d + j * 64) = p;
      }
    }
    __syncthreads();
    const int ci = w;
    f32x4 ac0 = {0.f,0.f,0.f,0.f}, ac1 = {0.f,0.f,0.f,0.f};
    const us* ar = Axs + r16 * 520 + g4 * 8;
    const us* bc = Bc + (ci * 16 + r16) * 520 + g4 * 8;
    #pragma unroll
    for (int f = 0; f < 16; f += 2) {
      ac0 = __builtin_amdgcn_mfma_f32_16x16x32_bf16(
              *(const s16x8*)(ar + f * 32), *(const s16x8*)(bc + f * 32), ac0, 0,0,0);
      ac1 = __builtin_amdgcn_mfma_f32_16x16x32_bf16(
              *(const s16x8*)(ar + f * 32 + 32), *(const s16x8*)(bc + f * 32 + 32), ac1, 0,0,0);
    }
    #pragma unroll
    for (int i = 0; i < 4; ++i)
      Y[(m0 + g4 * 4 + i) * HH + n0 + ci * 16 + r16] = ac0[i] + ac1[i];
    __syncthreads();
  }
}

extern "C" __global__ void gru_sentinel(float* out, float v) {
  if (blockIdx.x == 0 && threadIdx.x == 0) out[0] = v;
}

extern "C" void kernel_launch(void* const* d_in, const int* in_sizes, int n_in,
                              void* d_out, int out_size, void* d_ws, size_t ws_size,
                              hipStream_t stream) {
  const float* X  = (const float*)d_in[0];
  const float* GK = (const float*)d_in[1];
  const float* GB = (const float*)d_in[2];
  const float* CK = (const float*)d_in[3];
  const float* CB = (const float*)d_in[4];
  float* Y = (float*)d_out;
  unsigned char* wsb = (unsigned char*)d_ws;

  if (ws_size < (size_t)W_END) {
    gru_sentinel<<<1, 64, 0, stream>>>(Y, 1000.f + (float)(ws_size >> 20));
    return;
  }

  // zero counters/probe/flags + hb (h0 = 0) + rhb; deterministic each call
  hipMemsetAsync(d_ws, 0, W_END, stream);

  (void)hipFuncSetAttribute((const void*)xproj_c,
                            hipFuncAttributeMaxDynamicSharedMemorySize, XP_LDSB);
  xproj_c<<<dim3(16 * 64), dim3(256), XP_LDSB, stream>>>(X, CK, Y);

  (void)hipFuncSetAttribute((const void*)gru_persistent,
                            hipFuncAttributeMaxDynamicSharedMemorySize, LDS_BYTES);
  gru_persistent<<<dim3(256), dim3(256), LDS_BYTES, stream>>>(X, GK, GB, CK, CB, Y, wsb);
}

// Round 17
// 3609.399 us; speedup vs baseline: 1.0296x; 1.0296x over previous
//
#include <hip/hip_runtime.h>

// GRU layer, B=64 T=512 D=512 H=1024, TF GRUCell semantics.
// v17 = r10 (all-agent exchange, proven 2.88ms) + per-wave flags:
// producing wave drains itself (vmcnt) and sets its own agent flag; barriers
// S3/S6 deleted (4 barriers/step). Safety: rh flags follow S2 (which certifies
// ALL waves consumed hb into LDS), h flags follow S4 (same for rhb).
// All locality machinery dropped -- r11..r16 proved agent atomics win.

typedef __attribute__((ext_vector_type(8))) short          s16x8;
typedef __attribute__((ext_vector_type(4))) float          f32x4;
typedef __attribute__((ext_vector_type(4))) unsigned short us4;
typedef __attribute__((ext_vector_type(8))) unsigned short us8;
typedef unsigned long long ull;
typedef unsigned short us;

#define TT 512
#define DD 512
#define HH 1024
#define WPGE 1032
#define ASTR 1032
#define XSTR 520
#define O_ASH (64 * WPGE)                 // 66048
#define O_XS  (O_ASH + 8 * ASTR)          // 74304
#define O_USH (O_XS + 8 * XSTR)           // 78464 (float[8][36])
#define O_PS  (O_USH + 576)               // 79040 (float[2][8][20])
#define LDS_BYTES ((O_PS + 640) * 2)      // 159360
#define XP_LDSB (64 * 520 * 2 + 16 * 520 * 2)   // 83200

// ws layout (bytes)
#define W_FL   0             // island isl @ isl*8192: rA,rB,hA,hB 32x64B each
#define W_HB   65536         // h  bf16 [64][1024] -- memset 0 = h0
#define W_RHB  196608        // rh bf16 [64][1024]
#define W_END  327680
#define CAP_AG (1 << 17)

__device__ __forceinline__ us f2b(float f) {               // f32 -> bf16 RNE
  unsigned u = __float_as_uint(f);
  u += 0x7FFFu + ((u >> 16) & 1u);
  return (us)(u >> 16);
}
__device__ __forceinline__ float b2f(us b) { return __uint_as_float(((unsigned)b) << 16); }

__device__ __forceinline__ void drain_vm() {               // wave-wide drain
  asm volatile("s_waitcnt vmcnt(0)" ::: "memory");
}
__device__ __forceinline__ void pubfl(unsigned* p, unsigned v) {
  __hip_atomic_store(p, v, __ATOMIC_RELAXED, __HIP_MEMORY_SCOPE_AGENT);
}
__device__ __forceinline__ void pub8(ull* p, ull v) {
  __hip_atomic_store(p, v, __ATOMIC_RELAXED, __HIP_MEMORY_SCOPE_AGENT);
}
// wait flags in TWO 32-slot arrays (lanes 0-31 -> fA, 32-63 -> fB); agent poll
__device__ __forceinline__ void waitf2(const unsigned* fA, const unsigned* fB,
                                       unsigned e, int lane, bool& bad) {
  if (bad) return;
  const unsigned* p = (lane < 32) ? (fA + lane * 16) : (fB + (lane - 32) * 16);
  int n = 0;
  for (;;) {
    unsigned v = __hip_atomic_load(p, __ATOMIC_RELAXED, __HIP_MEMORY_SCOPE_AGENT);
    if (__all((int)(v >= e))) return;
    if (++n > CAP_AG) { bad = true; return; }
    __builtin_amdgcn_s_sleep(1);
  }
}
// stage 8 rows x 1024 bf16 island buffer -> Ash (thread: row8=tid>>5, lp=tid&31)
__device__ __forceinline__ void stage(const us* g, us* A, int row8, int lp) {
  const ull* p = (const ull*)(g + (size_t)row8 * HH) + lp;
  ull r[8];
  #pragma unroll
  for (int j = 0; j < 8; ++j)
    r[j] = __hip_atomic_load(p + j * 32, __ATOMIC_RELAXED, __HIP_MEMORY_SCOPE_AGENT);
  us* d = A + row8 * ASTR + lp * 4;
  #pragma unroll
  for (int j = 0; j < 8; ++j) *(ull*)(d + j * 128) = r[j];
}

// in-register 4x4 transpose within a lane quad -> 4 cols of row (r16&3)
__device__ __forceinline__ ull quad_pack(float v0, float v1, float v2, float v3, int q) {
  unsigned p01 = (unsigned)f2b(v0) | ((unsigned)f2b(v1) << 16);
  unsigned p23 = (unsigned)f2b(v2) | ((unsigned)f2b(v3) << 16);
  unsigned o01 = __shfl_xor(p01, 2);
  unsigned o23 = __shfl_xor(p23, 2);
  unsigned x = (q < 2) ? p01 : o23;
  unsigned y = (q < 2) ? o01 : p23;
  unsigned ux = __shfl_xor(x, 1);
  unsigned uy = __shfl_xor(y, 1);
  unsigned w0, w1;
  if (q & 1) { w0 = (ux >> 16) | (x & 0xFFFF0000u); w1 = (uy >> 16) | (y & 0xFFFF0000u); }
  else       { w0 = (x & 0xFFFFu) | (ux << 16);     w1 = (y & 0xFFFFu) | (uy << 16); }
  return (ull)w0 | ((ull)w1 << 32);
}

extern "C" __global__ void __launch_bounds__(256, 1)
gru_persistent(const float* __restrict__ X, const float* __restrict__ GK,
               const float* __restrict__ GB, const float* __restrict__ CK,
               const float* __restrict__ CB, float* __restrict__ Y,
               unsigned char* __restrict__ ws) {
  extern __shared__ us lds[];
  us*    Wg  = lds;                          // [64][WPGE]
  us*    Ash = lds + O_ASH;                  // [8][ASTR]
  us*    Xs  = lds + O_XS;                   // [8][XSTR]
  float* ush = (float*)(lds + O_USH);        // u [8][36]
  float* ps  = (float*)(lds + O_PS);         // cand partials [2][8][20]

  const int tid = threadIdx.x, bid = blockIdx.x;
  const int isl = bid & 7, iw = bid >> 3;    // island, WG-in-island (0..31)
  const int lane = tid & 63, w = tid >> 6;
  const int r16 = lane & 15, g4 = lane >> 4;
  const int row8 = tid >> 5, lp = tid & 31;
  const int cb = iw * 32;
  const int half = w & 1;
  const int tlB = w >> 1, khB = w & 1;

  unsigned* rA = (unsigned*)(ws + W_FL + (size_t)isl * 8192);
  unsigned* rB = rA + 512;                   // +2048 B
  unsigned* hA = rA + 1024;                  // +4096 B
  unsigned* hB = rA + 1536;                  // +6144 B
  us* hbI  = (us*)(ws + W_HB)  + (size_t)(isl * 8) * HH;
  us* rhbI = (us*)(ws + W_RHB) + (size_t)(isl * 8) * HH;

  // ---- weights -------------------------------------------------------------
  {   // gate h-part: LDS rows 0..31 = r cols cb.., rows 32..63 = u cols
    const int c = tid & 63;
    const size_t gcol = (c < 32) ? (size_t)(cb + c) : (size_t)(1024 + cb + (c - 32));
    for (int k = tid >> 6; k < 1024; k += 4)
      Wg[c * WPGE + k] = f2b(GK[(size_t)(512 + k) * 2048 + gcol]);
  }
  s16x8 wx[16], wc[16];
  {   // gate x-part (own col): waves 0,1 -> r cols; waves 2,3 -> u cols
    const size_t gx = (size_t)(cb + half * 16 + r16) + (w >= 2 ? 1024 : 0);
    #pragma unroll
    for (int c2 = 0; c2 < 16; ++c2) {
      us t0[8];
      #pragma unroll
      for (int e = 0; e < 8; ++e)
        t0[e] = f2b(GK[(size_t)(c2 * 32 + g4 * 8 + e) * 2048 + gx]);
      wx[c2] = (s16x8){(short)t0[0],(short)t0[1],(short)t0[2],(short)t0[3],
                       (short)t0[4],(short)t0[5],(short)t0[6],(short)t0[7]};
    }
  }
  {   // cand h-part (own col, K half khB)
    const size_t ccol = (size_t)(cb + tlB * 16 + r16);
    #pragma unroll
    for (int c2 = 0; c2 < 16; ++c2) {
      us t0[8];
      #pragma unroll
      for (int e = 0; e < 8; ++e)
        t0[e] = f2b(CK[(size_t)(512 + khB * 512 + c2 * 32 + g4 * 8 + e) * 1024 + ccol]);
      wc[c2] = (s16x8){(short)t0[0],(short)t0[1],(short)t0[2],(short)t0[3],
                       (short)t0[4],(short)t0[5],(short)t0[6],(short)t0[7]};
    }
  }
  const float biasG = (w < 2) ? GB[cb + half * 16 + r16]
                              : GB[1024 + cb + half * 16 + r16];
  const float biasC = CB[cb + tlB * 16 + r16];

  // ---- recurrence (4 barriers/step; per-wave flags) ------------------------
  float hreg[4] = {0.f, 0.f, 0.f, 0.f};
  bool bad = false;
  float4 px0, px1, px2, px3;
  {
    const float* s = X + (size_t)(isl * 8 + row8) * TT * DD + lp * 16;
    px0 = *(const float4*)s;       px1 = *(const float4*)(s + 4);
    px2 = *(const float4*)(s + 8); px3 = *(const float4*)(s + 12);
  }

  for (int t = 0; t < TT; ++t) {
    {   // Xs(t) from prefetch regs
      us* xd = Xs + row8 * XSTR + lp * 16;
      us8 v0 = { f2b(px0.x), f2b(px0.y), f2b(px0.z), f2b(px0.w),
                 f2b(px1.x), f2b(px1.y), f2b(px1.z), f2b(px1.w) };
      us8 v1 = { f2b(px2.x), f2b(px2.y), f2b(px2.z), f2b(px2.w),
                 f2b(px3.x), f2b(px3.y), f2b(px3.z), f2b(px3.w) };
      *(us8*)xd = v0; *(us8*)(xd + 8) = v1;
    }
    __syncthreads();                                              // S1

    f32x4 a0 = {0.f,0.f,0.f,0.f}, a1 = {0.f,0.f,0.f,0.f};
    {   // gate x-part (overlaps the h wait)
      const us* arX = Xs + (r16 & 7) * XSTR;
      #pragma unroll
      for (int c2 = 0; c2 < 16; c2 += 2) {
        a0 = __builtin_amdgcn_mfma_f32_16x16x32_bf16(
               *(const s16x8*)(arX + c2 * 32 + g4 * 8), wx[c2], a0, 0, 0, 0);
        a1 = __builtin_amdgcn_mfma_f32_16x16x32_bf16(
               *(const s16x8*)(arX + (c2 + 1) * 32 + g4 * 8), wx[c2 + 1], a1, 0, 0, 0);
      }
    }
    waitf2(hA, hB, (unsigned)t, lane, bad);             // h(t-1) ready
    stage(hbI, Ash, row8, lp);
    __syncthreads();                                              // S2

    {   // gate h-GEMM K=1024 (wave w -> Wg rows w*16..)
      const us* arB = Ash + (r16 & 7) * ASTR;
      const us* brB = Wg + (w * 16 + r16) * WPGE + g4 * 8;
      #pragma unroll
      for (int c2 = 0; c2 < 32; c2 += 2) {
        a0 = __builtin_amdgcn_mfma_f32_16x16x32_bf16(
               *(const s16x8*)(arB + c2 * 32 + g4 * 8),
               *(const s16x8*)(brB + c2 * 32), a0, 0, 0, 0);
        a1 = __builtin_amdgcn_mfma_f32_16x16x32_bf16(
               *(const s16x8*)(arB + (c2 + 1) * 32 + g4 * 8),
               *(const s16x8*)(brB + (c2 + 1) * 32), a1, 0, 0, 0);
      }
    }
    if (g4 < 2) {
      if (w < 2) {                         // r -> publish r*h (8B quad stores)
        const int colR = cb + half * 16 + r16;
        float rh[4];
        #pragma unroll
        for (int i = 0; i < 4; ++i) {      // C/D: row=g4*4+i, col=r16
          float gg = 1.f / (1.f + __expf(-(a0[i] + a1[i] + biasG)));
          rh[i] = gg * b2f(Ash[(g4 * 4 + i) * ASTR + colR]);
        }
        ull tv = quad_pack(rh[0], rh[1], rh[2], rh[3], r16 & 3);
        pub8((ull*)(rhbI + (size_t)(g4 * 4 + (r16 & 3)) * HH + cb + half * 16 + (r16 & ~3)),
             tv);
      } else {                             // u -> LDS (stays in-WG)
        const int uc = half * 16 + r16;
        #pragma unroll
        for (int i = 0; i < 4; ++i)
          ush[(g4 * 4 + i) * 36 + uc] = 1.f / (1.f + __expf(-(a0[i] + a1[i] + biasG)));
      }
    }
    // per-wave drain + flag (no barrier; S2 already certified hb reads done)
    if (w == 0) { drain_vm(); if (lane == 0) pubfl(rA + iw * 16, (unsigned)(t + 1)); }
    if (w == 1) { drain_vm(); if (lane == 0) pubfl(rB + iw * 16, (unsigned)(t + 1)); }

    // ---- phase B: cand over r*h ----
    float xc[4];                           // xp_c from Y slot t (overlaps wait)
    if (khB == 0 && g4 < 2) {
      const int colC = cb + tlB * 16 + r16;
      #pragma unroll
      for (int i = 0; i < 4; ++i)
        xc[i] = Y[((size_t)(isl * 8 + g4 * 4 + i) * TT + t) * HH + colC];
    }
    waitf2(rA, rB, (unsigned)(t + 1), lane, bad);
    stage(rhbI, Ash, row8, lp);
    __syncthreads();                                              // S4

    f32x4 c0 = {0.f,0.f,0.f,0.f}, c1 = {0.f,0.f,0.f,0.f};
    {
      const us* arC = Ash + (r16 & 7) * ASTR + khB * 512;
      #pragma unroll
      for (int c2 = 0; c2 < 16; c2 += 2) {
        c0 = __builtin_amdgcn_mfma_f32_16x16x32_bf16(
               *(const s16x8*)(arC + c2 * 32 + g4 * 8), wc[c2], c0, 0, 0, 0);
        c1 = __builtin_amdgcn_mfma_f32_16x16x32_bf16(
               *(const s16x8*)(arC + (c2 + 1) * 32 + g4 * 8), wc[c2 + 1], c1, 0, 0, 0);
      }
    }
    if (khB == 1 && g4 < 2) {              // partials K-half 1 -> LDS
      #pragma unroll
      for (int i = 0; i < 4; ++i)
        ps[tlB * 160 + (g4 * 4 + i) * 20 + r16] = c0[i] + c1[i];
    }
    __syncthreads();                                              // S5
    if (khB == 0 && g4 < 2) {              // blend + publish h
      const int colC = cb + tlB * 16 + r16;
      float hn[4];
      #pragma unroll
      for (int i = 0; i < 4; ++i) {
        int rr = g4 * 4 + i;
        float cv = tanhf(c0[i] + c1[i] + ps[tlB * 160 + rr * 20 + r16] + xc[i] + biasC);
        float uu = ush[rr * 36 + tlB * 16 + r16];
        hn[i] = uu * hreg[i] + (1.f - uu) * cv;
        hreg[i] = hn[i];
        Y[((size_t)(isl * 8 + rr) * TT + t) * HH + colC] = hn[i];
      }
      ull tv = quad_pack(hn[0], hn[1], hn[2], hn[3], r16 & 3);
      pub8((ull*)(hbI + (size_t)(g4 * 4 + (r16 & 3)) * HH + cb + tlB * 16 + (r16 & ~3)),
           tv);
    }
    // per-wave drain + flag (S4 already certified rhb reads done)
    if (w == 0) { drain_vm(); if (lane == 0) pubfl(hA + iw * 16, (unsigned)(t + 1)); }
    if (w == 2) { drain_vm(); if (lane == 0) pubfl(hB + iw * 16, (unsigned)(t + 1)); }

    if (t + 1 < TT) {                      // prefetch x(t+1) off the crit path
      const float* s = X + ((size_t)(isl * 8 + row8) * TT + (t + 1)) * DD + lp * 16;
      px0 = *(const float4*)s;       px1 = *(const float4*)(s + 4);
      px2 = *(const float4*)(s + 8); px3 = *(const float4*)(s + 12);
    }
  }
  if (bad && tid == 0) Y[1] = 31337.f;     // visible failure sentinel
}

// ---- one-time x-projection: Y <- f32(X[32768,512] @ CKc[512,1024]) ---------
extern "C" __global__ void __launch_bounds__(256, 1)
xproj_c(const float* __restrict__ X, const float* __restrict__ CK,
        float* __restrict__ Y) {
  extern __shared__ us lds[];
  us* Bc  = lds;                 // [64][520]
  us* Axs = lds + 64 * 520;      // [16][520]
  const int tid = threadIdx.x, lane = tid & 63, w = tid >> 6;
  const int r16 = lane & 15, g4 = lane >> 4;
  const int nt = blockIdx.x & 15, mb = blockIdx.x >> 4;
  const int n0 = nt * 64;
  const int srow = tid >> 4, slp = tid & 15;

  {
    const int c4 = (tid & 15) * 4;
    for (int k = tid >> 4; k < 512; k += 16) {
      float4 v = *(const float4*)(CK + (size_t)k * HH + n0 + c4);
      Bc[(c4 + 0) * 520 + k] = f2b(v.x);  Bc[(c4 + 1) * 520 + k] = f2b(v.y);
      Bc[(c4 + 2) * 520 + k] = f2b(v.z);  Bc[(c4 + 3) * 520 + k] = f2b(v.w);
    }
  }
  __syncthreads();

  for (int mt = 0; mt < 32; ++mt) {
    const size_t m0 = (size_t)mb * 512 + mt * 16;
    {
      const float* src = X + (m0 + srow) * 512 + slp * 4;
      us* d = Axs + srow * 520 + slp * 4;
      #pragma unroll
      for (int j = 0; j < 8; ++j) {
        float4 v = *(const float4*)(src + j * 64);
        us4 p = { f2b(v.x), f2b(v.y), f2b(v.z), f2b(v.w) };
        *(us4*)(d + j * 64) = p;
      }
    }
    __syncthreads();
    const int ci = w;
    f32x4 ac0 = {0.f,0.f,0.f,0.f}, ac1 = {0.f,0.f,0.f,0.f};
    const us* ar = Axs + r16 * 520 + g4 * 8;
    const us* bc = Bc + (ci * 16 + r16) * 520 + g4 * 8;
    #pragma unroll
    for (int f = 0; f < 16; f += 2) {
      ac0 = __builtin_amdgcn_mfma_f32_16x16x32_bf16(
              *(const s16x8*)(ar + f * 32), *(const s16x8*)(bc + f * 32), ac0, 0,0,0);
      ac1 = __builtin_amdgcn_mfma_f32_16x16x32_bf16(
              *(const s16x8*)(ar + f * 32 + 32), *(const s16x8*)(bc + f * 32 + 32), ac1, 0,0,0);
    }
    #pragma unroll
    for (int i = 0; i < 4; ++i)
      Y[(m0 + g4 * 4 + i) * HH + n0 + ci * 16 + r16] = ac0[i] + ac1[i];
    __syncthreads();
  }
}

extern "C" __global__ void gru_sentinel(float* out, float v) {
  if (blockIdx.x == 0 && threadIdx.x == 0) out[0] = v;
}

extern "C" void kernel_launch(void* const* d_in, const int* in_sizes, int n_in,
                              void* d_out, int out_size, void* d_ws, size_t ws_size,
                              hipStream_t stream) {
  const float* X  = (const float*)d_in[0];
  const float* GK = (const float*)d_in[1];
  const float* GB = (const float*)d_in[2];
  const float* CK = (const float*)d_in[3];
  const float* CB = (const float*)d_in[4];
  float* Y = (float*)d_out;
  unsigned char* wsb = (unsigned char*)d_ws;

  if (ws_size < (size_t)W_END) {
    gru_sentinel<<<1, 64, 0, stream>>>(Y, 1000.f + (float)(ws_size >> 20));
    return;
  }

  // zero flags + hb (h0 = 0) + rhb; deterministic each call
  hipMemsetAsync(d_ws, 0, W_END, stream);

  (void)hipFuncSetAttribute((const void*)xproj_c,
                            hipFuncAttributeMaxDynamicSharedMemorySize, XP_LDSB);
  xproj_c<<<dim3(16 * 64), dim3(256), XP_LDSB, stream>>>(X, CK, Y);

  (void)hipFuncSetAttribute((const void*)gru_persistent,
                            hipFuncAttributeMaxDynamicSharedMemorySize, LDS_BYTES);
  gru_persistent<<<dim3(256), dim3(256), LDS_BYTES, stream>>>(X, GK, GB, CK, CB, Y, wsb);
}

// Round 18
// 3035.576 us; speedup vs baseline: 1.2242x; 1.1890x over previous
//
#include <hip/hip_runtime.h>

// GRU layer, B=64 T=512 D=512 H=1024, TF GRUCell semantics.
// v18 = r10 verbatim (the measured champion, 2.88ms gru / 2.95ms total).
// Merged-WG structure (every WG: gates r+u then cand for its 32 cols),
// 8 islands x 8 batch rows x 32 WGs. All cross-WG exchange via relaxed
// agent-scope __hip_atomic ops. 6 barriers/step (S3/S6 before flags keep
// waves phase-converged -- r17 proved removing them costs 0.6ms).
// r11-r16 proved all XCD-locality schemes (sc0/buffer_inv) are slower.
// Step time 5.6us = 2 agent all-to-all handoffs (~2.2us) + ~1.2us compute:
// sync-latency floor for this recurrence from HIP.

typedef __attribute__((ext_vector_type(8))) short          s16x8;
typedef __attribute__((ext_vector_type(4))) float          f32x4;
typedef __attribute__((ext_vector_type(4))) unsigned short us4;
typedef __attribute__((ext_vector_type(8))) unsigned short us8;
typedef unsigned long long ull;
typedef unsigned short us;

#define TT 512
#define DD 512
#define HH 1024
#define WPGE 1032
#define ASTR 1032
#define XSTR 520
#define O_ASH (64 * WPGE)                 // 66048
#define O_XS  (O_ASH + 8 * ASTR)          // 74304
#define O_USH (O_XS + 8 * XSTR)           // 78464 (float[8][36])
#define O_PS  (O_USH + 576)               // 79040 (float[2][8][20])
#define LDS_BYTES ((O_PS + 640) * 2)      // 159360
#define XP_LDSB (64 * 520 * 2 + 16 * 520 * 2)   // 83200

// ws layout (bytes)
#define W_FL   0             // island isl @ isl*4096: hfl 32x64B, rfl @+2048
#define W_HB   32768         // h  bf16 [64][1024] (131072 B) -- memset 0 = h0
#define W_RHB  163840        // rh bf16 [64][1024]
#define W_END  294912
#define POLLCAP (1 << 17)

__device__ __forceinline__ us f2b(float f) {               // f32 -> bf16 RNE
  unsigned u = __float_as_uint(f);
  u += 0x7FFFu + ((u >> 16) & 1u);
  return (us)(u >> 16);
}
__device__ __forceinline__ float b2f(us b) { return __uint_as_float(((unsigned)b) << 16); }

// wait all 32 island flags >= e (uniform per wave; sticky-bad, no hang)
__device__ __forceinline__ void waitf(const unsigned* f, unsigned e, int lane, bool& bad) {
  if (bad) return;
  const unsigned* p = f + (lane & 31) * 16;                // 64B-spaced slots
  int n = 0;
  for (;;) {
    unsigned v = (lane < 32)
        ? __hip_atomic_load(p, __ATOMIC_RELAXED, __HIP_MEMORY_SCOPE_AGENT) : e;
    if (__all((int)(v >= e))) return;
    if (++n > POLLCAP) { bad = true; return; }
    __builtin_amdgcn_s_sleep(1);
  }
}

// stage 8 rows x 1024 bf16 island buffer -> Ash (thread: row8=tid>>5, lp=tid&31)
__device__ __forceinline__ void stage(const us* g, us* A, int row8, int lp) {
  const ull* p = (const ull*)(g + (size_t)row8 * HH) + lp;
  ull r[8];
  #pragma unroll
  for (int j = 0; j < 8; ++j)
    r[j] = __hip_atomic_load(p + j * 32, __ATOMIC_RELAXED, __HIP_MEMORY_SCOPE_AGENT);
  us* d = A + row8 * ASTR + lp * 4;
  #pragma unroll
  for (int j = 0; j < 8; ++j) *(ull*)(d + j * 128) = r[j];
}

// in-register 4x4 transpose within a lane quad -> 4 cols of row (r16&3)
__device__ __forceinline__ ull quad_pack(float v0, float v1, float v2, float v3, int q) {
  unsigned p01 = (unsigned)f2b(v0) | ((unsigned)f2b(v1) << 16);
  unsigned p23 = (unsigned)f2b(v2) | ((unsigned)f2b(v3) << 16);
  unsigned o01 = __shfl_xor(p01, 2);
  unsigned o23 = __shfl_xor(p23, 2);
  unsigned x = (q < 2) ? p01 : o23;
  unsigned y = (q < 2) ? o01 : p23;
  unsigned ux = __shfl_xor(x, 1);
  unsigned uy = __shfl_xor(y, 1);
  unsigned w0, w1;
  if (q & 1) { w0 = (ux >> 16) | (x & 0xFFFF0000u); w1 = (uy >> 16) | (y & 0xFFFF0000u); }
  else       { w0 = (x & 0xFFFFu) | (ux << 16);     w1 = (y & 0xFFFFu) | (uy << 16); }
  return (ull)w0 | ((ull)w1 << 32);
}

extern "C" __global__ void __launch_bounds__(256, 1)
gru_persistent(const float* __restrict__ X, const float* __restrict__ GK,
               const float* __restrict__ GB, const float* __restrict__ CK,
               const float* __restrict__ CB, float* __restrict__ Y,
               unsigned char* __restrict__ ws) {
  extern __shared__ us lds[];
  us*    Wg  = lds;                          // [64][WPGE] gate h-part (r|u cols)
  us*    Ash = lds + O_ASH;                  // [8][ASTR]
  us*    Xs  = lds + O_XS;                   // [8][XSTR]
  float* ush = (float*)(lds + O_USH);        // u [8][36]
  float* ps  = (float*)(lds + O_PS);         // cand partials [2][8][20]

  const int tid = threadIdx.x, bid = blockIdx.x;
  const int isl = bid & 7, iw = bid >> 3;    // island, WG-in-island (0..31)
  const int lane = tid & 63, w = tid >> 6;
  const int r16 = lane & 15, g4 = lane >> 4;
  const int row8 = tid >> 5, lp = tid & 31;  // staging map
  const int cb = iw * 32;                    // this WG's 32 columns
  const int half = w & 1;                    // gate col-tile within wave pair
  const int tlB = w >> 1, khB = w & 1;       // cand: tile, K-half

  unsigned* hfl = (unsigned*)(ws + (size_t)isl * 4096);
  unsigned* rfl = hfl + 512;                 // +2048 B
  us* hbI  = (us*)(ws + W_HB)  + (size_t)(isl * 8) * HH;
  us* rhbI = (us*)(ws + W_RHB) + (size_t)(isl * 8) * HH;

  // ---- weights -------------------------------------------------------------
  {   // gate h-part: LDS rows 0..31 = r cols cb.., rows 32..63 = u cols
    const int c = tid & 63;
    const size_t gcol = (c < 32) ? (size_t)(cb + c) : (size_t)(1024 + cb + (c - 32));
    for (int k = tid >> 6; k < 1024; k += 4)
      Wg[c * WPGE + k] = f2b(GK[(size_t)(512 + k) * 2048 + gcol]);
  }
  s16x8 wx[16], wc[16];
  {   // gate x-part (own col): waves 0,1 -> r cols; waves 2,3 -> u cols
    const size_t gx = (size_t)(cb + half * 16 + r16) + (w >= 2 ? 1024 : 0);
    #pragma unroll
    for (int c2 = 0; c2 < 16; ++c2) {
      us t0[8];
      #pragma unroll
      for (int e = 0; e < 8; ++e)
        t0[e] = f2b(GK[(size_t)(c2 * 32 + g4 * 8 + e) * 2048 + gx]);
      wx[c2] = (s16x8){(short)t0[0],(short)t0[1],(short)t0[2],(short)t0[3],
                       (short)t0[4],(short)t0[5],(short)t0[6],(short)t0[7]};
    }
  }
  {   // cand h-part (own col, K half khB)
    const size_t ccol = (size_t)(cb + tlB * 16 + r16);
    #pragma unroll
    for (int c2 = 0; c2 < 16; ++c2) {
      us t0[8];
      #pragma unroll
      for (int e = 0; e < 8; ++e)
        t0[e] = f2b(CK[(size_t)(512 + khB * 512 + c2 * 32 + g4 * 8 + e) * 1024 + ccol]);
      wc[c2] = (s16x8){(short)t0[0],(short)t0[1],(short)t0[2],(short)t0[3],
                       (short)t0[4],(short)t0[5],(short)t0[6],(short)t0[7]};
    }
  }
  const float biasG = (w < 2) ? GB[cb + half * 16 + r16]
                              : GB[1024 + cb + half * 16 + r16];
  const float biasC = CB[cb + tlB * 16 + r16];

  // ---- recurrence ----------------------------------------------------------
  float hreg[4] = {0.f, 0.f, 0.f, 0.f};
  bool bad = false;
  float4 px0, px1, px2, px3;
  {
    const float* s = X + (size_t)(isl * 8 + row8) * TT * DD + lp * 16;
    px0 = *(const float4*)s;       px1 = *(const float4*)(s + 4);
    px2 = *(const float4*)(s + 8); px3 = *(const float4*)(s + 12);
  }

  for (int t = 0; t < TT; ++t) {
    {   // Xs(t) from prefetch regs
      us* xd = Xs + row8 * XSTR + lp * 16;
      us8 v0 = { f2b(px0.x), f2b(px0.y), f2b(px0.z), f2b(px0.w),
                 f2b(px1.x), f2b(px1.y), f2b(px1.z), f2b(px1.w) };
      us8 v1 = { f2b(px2.x), f2b(px2.y), f2b(px2.z), f2b(px2.w),
                 f2b(px3.x), f2b(px3.y), f2b(px3.z), f2b(px3.w) };
      *(us8*)xd = v0; *(us8*)(xd + 8) = v1;
    }
    __syncthreads();                                              // S1

    // gate x-part (overlaps the h wait)
    f32x4 a0 = {0.f,0.f,0.f,0.f}, a1 = {0.f,0.f,0.f,0.f};
    {
      const us* arX = Xs + (r16 & 7) * XSTR;
      #pragma unroll
      for (int c2 = 0; c2 < 16; c2 += 2) {
        a0 = __builtin_amdgcn_mfma_f32_16x16x32_bf16(
               *(const s16x8*)(arX + c2 * 32 + g4 * 8), wx[c2], a0, 0, 0, 0);
        a1 = __builtin_amdgcn_mfma_f32_16x16x32_bf16(
               *(const s16x8*)(arX + (c2 + 1) * 32 + g4 * 8), wx[c2 + 1], a1, 0, 0, 0);
      }
    }
    waitf(hfl, (unsigned)t, lane, bad);                 // h(t-1) ready
    stage(hbI, Ash, row8, lp);
    __syncthreads();                                              // S2

    {   // gate h-GEMM K=1024 (wave w -> Wg rows w*16..)
      const us* arB = Ash + (r16 & 7) * ASTR;
      const us* brB = Wg + (w * 16 + r16) * WPGE + g4 * 8;
      #pragma unroll
      for (int c2 = 0; c2 < 32; c2 += 2) {
        a0 = __builtin_amdgcn_mfma_f32_16x16x32_bf16(
               *(const s16x8*)(arB + c2 * 32 + g4 * 8),
               *(const s16x8*)(brB + c2 * 32), a0, 0, 0, 0);
        a1 = __builtin_amdgcn_mfma_f32_16x16x32_bf16(
               *(const s16x8*)(arB + (c2 + 1) * 32 + g4 * 8),
               *(const s16x8*)(brB + (c2 + 1) * 32), a1, 0, 0, 0);
      }
    }
    if (g4 < 2) {
      if (w < 2) {                         // r -> publish r*h (8B quad stores)
        const int colR = cb + half * 16 + r16;
        float rh[4];
        #pragma unroll
        for (int i = 0; i < 4; ++i) {      // C/D: row=g4*4+i, col=r16
          float gg = 1.f / (1.f + __expf(-(a0[i] + a1[i] + biasG)));
          rh[i] = gg * b2f(Ash[(g4 * 4 + i) * ASTR + colR]);
        }
        ull tv = quad_pack(rh[0], rh[1], rh[2], rh[3], r16 & 3);
        __hip_atomic_store(
            (ull*)(rhbI + (size_t)(g4 * 4 + (r16 & 3)) * HH + cb + half * 16 + (r16 & ~3)),
            tv, __ATOMIC_RELAXED, __HIP_MEMORY_SCOPE_AGENT);
      } else {                             // u -> LDS (stays in-WG)
        const int uc = half * 16 + r16;
        #pragma unroll
        for (int i = 0; i < 4; ++i)
          ush[(g4 * 4 + i) * 36 + uc] = 1.f / (1.f + __expf(-(a0[i] + a1[i] + biasG)));
      }
    }
    __syncthreads();                       // S3: vmcnt drain -> rh visible
    if (tid == 0)
      __hip_atomic_store(rfl + iw * 16, (unsigned)(t + 1),
                         __ATOMIC_RELAXED, __HIP_MEMORY_SCOPE_AGENT);

    // ---- phase B: cand over r*h ----
    float xc[4];                           // f32 xp_c from Y slot t (pre-wait)
    if (khB == 0 && g4 < 2) {
      const int colC = cb + tlB * 16 + r16;
      #pragma unroll
      for (int i = 0; i < 4; ++i)
        xc[i] = Y[((size_t)(isl * 8 + g4 * 4 + i) * TT + t) * HH + colC];
    }
    waitf(rfl, (unsigned)(t + 1), lane, bad);
    stage(rhbI, Ash, row8, lp);
    __syncthreads();                                              // S4

    f32x4 c0 = {0.f,0.f,0.f,0.f}, c1 = {0.f,0.f,0.f,0.f};
    {
      const us* arC = Ash + (r16 & 7) * ASTR + khB * 512;
      #pragma unroll
      for (int c2 = 0; c2 < 16; c2 += 2) {
        c0 = __builtin_amdgcn_mfma_f32_16x16x32_bf16(
               *(const s16x8*)(arC + c2 * 32 + g4 * 8), wc[c2], c0, 0, 0, 0);
        c1 = __builtin_amdgcn_mfma_f32_16x16x32_bf16(
               *(const s16x8*)(arC + (c2 + 1) * 32 + g4 * 8), wc[c2 + 1], c1, 0, 0, 0);
      }
    }
    if (khB == 1 && g4 < 2) {              // partials K-half 1 -> LDS
      #pragma unroll
      for (int i = 0; i < 4; ++i)
        ps[tlB * 160 + (g4 * 4 + i) * 20 + r16] = c0[i] + c1[i];
    }
    __syncthreads();                                              // S5
    if (khB == 0 && g4 < 2) {              // blend + publish h
      const int colC = cb + tlB * 16 + r16;
      float hn[4];
      #pragma unroll
      for (int i = 0; i < 4; ++i) {
        int rr = g4 * 4 + i;
        float cv = tanhf(c0[i] + c1[i] + ps[tlB * 160 + rr * 20 + r16] + xc[i] + biasC);
        float uu = ush[rr * 36 + tlB * 16 + r16];
        hn[i] = uu * hreg[i] + (1.f - uu) * cv;
        hreg[i] = hn[i];
        Y[((size_t)(isl * 8 + rr) * TT + t) * HH + colC] = hn[i];
      }
      ull tv = quad_pack(hn[0], hn[1], hn[2], hn[3], r16 & 3);
      __hip_atomic_store(
          (ull*)(hbI + (size_t)(g4 * 4 + (r16 & 3)) * HH + cb + tlB * 16 + (r16 & ~3)),
          tv, __ATOMIC_RELAXED, __HIP_MEMORY_SCOPE_AGENT);
    }
    if (t + 1 < TT) {                      // prefetch x(t+1)
      const float* s = X + ((size_t)(isl * 8 + row8) * TT + (t + 1)) * DD + lp * 16;
      px0 = *(const float4*)s;       px1 = *(const float4*)(s + 4);
      px2 = *(const float4*)(s + 8); px3 = *(const float4*)(s + 12);
    }
    __syncthreads();                       // S6: vmcnt drain -> h visible
    if (tid == 0)
      __hip_atomic_store(hfl + iw * 16, (unsigned)(t + 1),
                         __ATOMIC_RELAXED, __HIP_MEMORY_SCOPE_AGENT);
  }
  if (bad && tid == 0) Y[1] = 31337.f;     // visible failure sentinel
}

// ---- one-time x-projection: Y <- f32(X[32768,512] @ CKc[512,1024]) ---------
extern "C" __global__ void __launch_bounds__(256, 1)
xproj_c(const float* __restrict__ X, const float* __restrict__ CK,
        float* __restrict__ Y) {
  extern __shared__ us lds[];
  us* Bc  = lds;                 // [64][520]
  us* Axs = lds + 64 * 520;      // [16][520]
  const int tid = threadIdx.x, lane = tid & 63, w = tid >> 6;
  const int r16 = lane & 15, g4 = lane >> 4;
  const int nt = blockIdx.x & 15, mb = blockIdx.x >> 4;
  const int n0 = nt * 64;
  const int srow = tid >> 4, slp = tid & 15;

  {
    const int c4 = (tid & 15) * 4;
    for (int k = tid >> 4; k < 512; k += 16) {
      float4 v = *(const float4*)(CK + (size_t)k * HH + n0 + c4);
      Bc[(c4 + 0) * 520 + k] = f2b(v.x);  Bc[(c4 + 1) * 520 + k] = f2b(v.y);
      Bc[(c4 + 2) * 520 + k] = f2b(v.z);  Bc[(c4 + 3) * 520 + k] = f2b(v.w);
    }
  }
  __syncthreads();

  for (int mt = 0; mt < 32; ++mt) {
    const size_t m0 = (size_t)mb * 512 + mt * 16;
    {                                      // stage A [16][512] f32->bf16
      const float* src = X + (m0 + srow) * 512 + slp * 4;
      us* d = Axs + srow * 520 + slp * 4;
      #pragma unroll
      for (int j = 0; j < 8; ++j) {
        float4 v = *(const float4*)(src + j * 64);
        us4 p = { f2b(v.x), f2b(v.y), f2b(v.z), f2b(v.w) };
        *(us4*)(d + j * 64) = p;
      }
    }
    __syncthreads();
    const int ci = w;
    f32x4 ac0 = {0.f,0.f,0.f,0.f}, ac1 = {0.f,0.f,0.f,0.f};
    const us* ar = Axs + r16 * 520 + g4 * 8;
    const us* bc = Bc + (ci * 16 + r16) * 520 + g4 * 8;
    #pragma unroll
    for (int f = 0; f < 16; f += 2) {
      ac0 = __builtin_amdgcn_mfma_f32_16x16x32_bf16(
              *(const s16x8*)(ar + f * 32), *(const s16x8*)(bc + f * 32), ac0, 0,0,0);
      ac1 = __builtin_amdgcn_mfma_f32_16x16x32_bf16(
              *(const s16x8*)(ar + f * 32 + 32), *(const s16x8*)(bc + f * 32 + 32), ac1, 0,0,0);
    }
    #pragma unroll
    for (int i = 0; i < 4; ++i)
      Y[(m0 + g4 * 4 + i) * HH + n0 + ci * 16 + r16] = ac0[i] + ac1[i];
    __syncthreads();
  }
}

extern "C" __global__ void gru_sentinel(float* out, float v) {
  if (blockIdx.x == 0 && threadIdx.x == 0) out[0] = v;
}

extern "C" void kernel_launch(void* const* d_in, const int* in_sizes, int n_in,
                              void* d_out, int out_size, void* d_ws, size_t ws_size,
                              hipStream_t stream) {
  const float* X  = (const float*)d_in[0];
  const float* GK = (const float*)d_in[1];
  const float* GB = (const float*)d_in[2];
  const float* CK = (const float*)d_in[3];
  const float* CB = (const float*)d_in[4];
  float* Y = (float*)d_out;
  unsigned char* wsb = (unsigned char*)d_ws;

  if (ws_size < (size_t)W_END) {
    gru_sentinel<<<1, 64, 0, stream>>>(Y, 1000.f + (float)(ws_size >> 20));
    return;
  }

  // zero flags + hb (h0 = 0) + rhb; deterministic each call
  hipMemsetAsync(d_ws, 0, W_END, stream);

  (void)hipFuncSetAttribute((const void*)xproj_c,
                            hipFuncAttributeMaxDynamicSharedMemorySize, XP_LDSB);
  xproj_c<<<dim3(16 * 64), dim3(256), XP_LDSB, stream>>>(X, CK, Y);

  (void)hipFuncSetAttribute((const void*)gru_persistent,
                            hipFuncAttributeMaxDynamicSharedMemorySize, LDS_BYTES);
  gru_persistent<<<dim3(256), dim3(256), LDS_BYTES, stream>>>(X, GK, GB, CK, CB, Y, wsb);
}